// Round 4
// baseline (1800.374 us; speedup 1.0000x reference)
//
#include <hip/hip_runtime.h>
#include <hip/hip_bf16.h>
#include <math.h>

#define BN_EPS 1e-5f

typedef __bf16 bf8 __attribute__((ext_vector_type(8)));
typedef unsigned short us8 __attribute__((ext_vector_type(8)));
typedef float f32x4 __attribute__((ext_vector_type(4)));

// ---------- helpers ----------
static __device__ __forceinline__ unsigned short f2bf(float f) {
  unsigned int u = __float_as_uint(f);
  unsigned int r = (u + 0x7FFFu + ((u >> 16) & 1u)) >> 16;   // RNE
  return (unsigned short)r;
}
static __device__ __forceinline__ float bf2f(unsigned short v) {
  return __uint_as_float(((unsigned int)v) << 16);
}
static __device__ __forceinline__ float sigmoidf_(float x) {
  return 1.0f / (1.0f + __expf(-x));
}
static __device__ __forceinline__ float softplusf_(float x) {
  return fmaxf(x, 0.0f) + log1pf(__expf(-fabsf(x)));
}

// ---------- kernels ----------

// zero degree array + stats accumulators
__global__ void k_zero(int* __restrict__ deg, float* __restrict__ stats, int N) {
  int stride = gridDim.x * blockDim.x;
  int i = blockIdx.x * blockDim.x + threadIdx.x;
  for (int j = i; j < N; j += stride) deg[j] = 0;
  for (int j = i; j < 768; j += stride) stats[j] = 0.f;
}

// degree count over src = edge_index[0], int4 loads
__global__ void k_deg(const int* __restrict__ ei, int* __restrict__ deg, int E) {
  int idx = blockIdx.x * 256 + threadIdx.x;
  int e = idx * 4;
  if (e + 3 < E) {
    int4 v = *(const int4*)(ei + e);
    atomicAdd(&deg[v.x], 1);
    atomicAdd(&deg[v.y], 1);
    atomicAdd(&deg[v.z], 1);
    atomicAdd(&deg[v.w], 1);
  } else if (e < E) {
    for (int k = e; k < E && k < e + 4; ++k) atomicAdd(&deg[ei[k]], 1);
  }
}

// exclusive scan of deg -> offs, copy -> cursor. Single block, 4 elems/thread.
__global__ __launch_bounds__(1024) void k_scan(const int* __restrict__ deg,
                                               int* __restrict__ offs,
                                               int* __restrict__ cursor, int N) {
  __shared__ int wsum[16];
  __shared__ int carry_s;
  int tid = threadIdx.x;
  int lane = tid & 63, wv = tid >> 6;
  if (tid == 0) carry_s = 0;
  __syncthreads();
  int N4 = (N + 3) >> 2;
  for (int b4 = 0; b4 < N4; b4 += 1024) {
    int i4 = b4 + tid;
    int4 v = make_int4(0, 0, 0, 0);
    int base = i4 * 4;
    if (i4 < N4) {
      if (base + 3 < N) v = *(const int4*)(deg + base);
      else {
        v.x = deg[base];
        if (base + 1 < N) v.y = deg[base + 1];
        if (base + 2 < N) v.z = deg[base + 2];
      }
    }
    int tsum = v.x + v.y + v.z + v.w;
    int x = tsum;
    #pragma unroll
    for (int off = 1; off < 64; off <<= 1) {
      int t = __shfl_up(x, off, 64);
      if (lane >= off) x += t;
    }
    if (lane == 63) wsum[wv] = x;
    __syncthreads();
    if (wv == 0 && lane < 16) {
      int y = wsum[lane];
      #pragma unroll
      for (int off = 1; off < 16; off <<= 1) {
        int t = __shfl_up(y, off, 64);
        if (lane >= off) y += t;
      }
      wsum[lane] = y;   // inclusive over waves
    }
    __syncthreads();
    int carry = carry_s;
    int pre = carry + ((wv == 0) ? 0 : wsum[wv - 1]) + (x - tsum);
    if (i4 < N4) {
      int o0 = pre, o1 = o0 + v.x, o2 = o1 + v.y, o3 = o2 + v.z;
      if (base + 3 < N) {
        *(int4*)(offs + base) = make_int4(o0, o1, o2, o3);
        *(int4*)(cursor + base) = make_int4(o0, o1, o2, o3);
      } else {
        offs[base] = o0; cursor[base] = o0;
        if (base + 1 < N) { offs[base + 1] = o1; cursor[base + 1] = o1; }
        if (base + 2 < N) { offs[base + 2] = o2; cursor[base + 2] = o2; }
      }
    }
    __syncthreads();
    if (tid == 1023) carry_s = carry + wsum[15];
    __syncthreads();
  }
}

// Build WT12 [512 cols][128 k] bf16 (P-GEMM A operand) and W3T [256 cols][64 k] bf16.
// WT12[cc][k] = W[(cc<256 ? k : k+128)][cc&255];  W3T[c][k] = W[256+k][c]
__global__ __launch_bounds__(256) void k_wt(const float* __restrict__ W,
                                            unsigned short* __restrict__ WT12,
                                            unsigned short* __restrict__ W3T) {
  int idx = blockIdx.x * 256 + threadIdx.x;    // 0 .. 81919
  if (idx < 65536) {
    int cc = idx >> 7, k = idx & 127;
    int row = (cc < 256) ? k : (k + 128);
    WT12[cc * 128 + k] = f2bf(W[(size_t)row * 256 + (cc & 255)]);
  } else {
    int j = idx - 65536;
    int c = j >> 6, k = j & 63;
    W3T[c * 64 + k] = f2bf(W[(size_t)(256 + k) * 256 + c]);
  }
}

// P = x @ [W1|W2] -> bf16 [N][512]. grid (ceil(N/64), 2), block 256 (4 waves).
__global__ __launch_bounds__(256) void k_pgemm(const float* __restrict__ x,
                                               const unsigned short* __restrict__ WT12,
                                               unsigned short* __restrict__ P, int N) {
  __shared__ unsigned short xs[64][136];   // [row][k], stride 272B (16B-aligned, 2-way banks)
  int row0 = blockIdx.x * 64;
  int half = blockIdx.y;                   // cols half*256 ..
  int tid = threadIdx.x;
  for (int i = tid; i < 2048; i += 256) {  // 64 rows x 32 float4
    int r = i >> 5, c4 = (i & 31) * 4;
    int gr = row0 + r;
    float4 v = make_float4(0.f, 0.f, 0.f, 0.f);
    if (gr < N) v = *(const float4*)(x + (size_t)gr * 128 + c4);
    ushort4 h = {f2bf(v.x), f2bf(v.y), f2bf(v.z), f2bf(v.w)};
    *(ushort4*)&xs[r][c4] = h;
  }
  __syncthreads();
  int w = tid >> 6, l = tid & 63, l15 = l & 15, lg = l >> 4;
  f32x4 acc[4][4] = {};                    // [ctl][nt]
  const unsigned short* wtb = WT12 + (size_t)(half * 256 + w * 64 + l15) * 128 + lg * 8;
  #pragma unroll
  for (int k0 = 0; k0 < 4; ++k0) {
    bf8 bfr[4];
    #pragma unroll
    for (int nt = 0; nt < 4; ++nt) {
      us8 raw = *(const us8*)&xs[nt * 16 + l15][k0 * 32 + lg * 8];
      bfr[nt] = __builtin_bit_cast(bf8, raw);
    }
    #pragma unroll
    for (int ctl = 0; ctl < 4; ++ctl) {
      us8 araw = *(const us8*)(wtb + (size_t)ctl * (16 * 128) + k0 * 32);
      bf8 afr = __builtin_bit_cast(bf8, araw);
      #pragma unroll
      for (int nt = 0; nt < 4; ++nt)
        acc[ctl][nt] = __builtin_amdgcn_mfma_f32_16x16x32_bf16(afr, bfr[nt], acc[ctl][nt], 0, 0, 0);
    }
  }
  #pragma unroll
  for (int ctl = 0; ctl < 4; ++ctl) {
    int pcol = half * 256 + w * 64 + ctl * 16 + lg * 4;
    #pragma unroll
    for (int nt = 0; nt < 4; ++nt) {
      int prow = row0 + nt * 16 + l15;
      if (prow < N) {
        f32x4 a = acc[ctl][nt];
        ushort4 hv = {f2bf(a[0]), f2bf(a[1]), f2bf(a[2]), f2bf(a[3])};
        *(ushort4*)(P + (size_t)prow * 512 + pcol) = hv;
      }
    }
  }
}

// Fused edge kernel: per 64-edge tile: Q = ea@W3 (MFMA, W3T LDS-resident),
// gated = Q + P1[src] + P2[dst]; accumulate BN1 sums; bf16 row -> CSR slot.
// Grid-stride over tiles; block 256 = 4 waves; wave w owns cols w*64..w*64+63.
__global__ __launch_bounds__(256, 3) void k_fuse(
    const int* __restrict__ ei, const float* __restrict__ ea,
    const unsigned short* __restrict__ W3T, const unsigned short* __restrict__ P,
    unsigned short* __restrict__ gated, int* __restrict__ cursor,
    float* __restrict__ stats, int E, int ntiles) {
  __shared__ unsigned short w3s[256][72];   // [col][k] 36 KB, 16B-aligned rows
  __shared__ unsigned short eas[64][72];    // [edge][k] 9 KB
  __shared__ int ssrc[64], sdst[64], spos[64];
  int tid = threadIdx.x;
  int w = tid >> 6, l = tid & 63, l15 = l & 15, lg = l >> 4;

  // stage W3T once per block (32 KB, L2-hot)
  for (int i = tid; i < 2048; i += 256) {   // 256 cols x 8 chunks of 8 bf16
    int c = i >> 3, k8 = (i & 7) * 8;
    *(us8*)&w3s[c][k8] = *(const us8*)(W3T + c * 64 + k8);
  }

  float sA[16] = {}, qA[16] = {};           // per-lane BN1 partials (cols w*64+ctl*16+lg*4+j)

  for (int t = blockIdx.x; t < ntiles; t += gridDim.x) {
    int e0 = t * 64;
    __syncthreads();                        // prev tile's LDS readers done / W3T staged
    if (tid < 64) {
      int e = e0 + tid;
      int s = 0, d = 0, p = 0;
      if (e < E) {
        s = ei[e]; d = ei[E + e];
        p = atomicAdd(&cursor[s], 1);
      }
      ssrc[tid] = s; sdst[tid] = d; spos[tid] = p;
    }
    for (int i = tid; i < 1024; i += 256) { // 64 edges x 16 float4
      int r = i >> 4, c4 = (i & 15) * 4;
      int e = e0 + r;
      float4 v = make_float4(0.f, 0.f, 0.f, 0.f);
      if (e < E) v = *(const float4*)(ea + (size_t)e * 64 + c4);
      ushort4 h = {f2bf(v.x), f2bf(v.y), f2bf(v.z), f2bf(v.w)};
      *(ushort4*)&eas[r][c4] = h;
    }
    __syncthreads();

    // Q = ea @ W3 : A = W3T[col][k], B = eas[edge][k]; D[col][edge]
    f32x4 acc[4][4] = {};                   // [ctl][nt]
    #pragma unroll
    for (int k0 = 0; k0 < 2; ++k0) {
      bf8 bfr[4];
      #pragma unroll
      for (int nt = 0; nt < 4; ++nt) {
        us8 raw = *(const us8*)&eas[nt * 16 + l15][k0 * 32 + lg * 8];
        bfr[nt] = __builtin_bit_cast(bf8, raw);
      }
      #pragma unroll
      for (int ctl = 0; ctl < 4; ++ctl) {
        us8 araw = *(const us8*)&w3s[w * 64 + ctl * 16 + l15][k0 * 32 + lg * 8];
        bf8 afr = __builtin_bit_cast(bf8, araw);
        #pragma unroll
        for (int nt = 0; nt < 4; ++nt)
          acc[ctl][nt] = __builtin_amdgcn_mfma_f32_16x16x32_bf16(afr, bfr[nt], acc[ctl][nt], 0, 0, 0);
      }
    }

    // epilogue: + P1[src] + P2[dst], stats, bf16 store to CSR slot
    int sp_[4], sn_[4], dn_[4], ok_[4];
    #pragma unroll
    for (int nt = 0; nt < 4; ++nt) {
      int el = nt * 16 + l15;
      sp_[nt] = spos[el]; sn_[nt] = ssrc[el]; dn_[nt] = sdst[el];
      ok_[nt] = (e0 + el < E);
    }
    #pragma unroll
    for (int ctl = 0; ctl < 4; ++ctl) {
      int coff = w * 64 + ctl * 16 + lg * 4;
      uint2 p1[4], p2[4];
      #pragma unroll
      for (int nt = 0; nt < 4; ++nt)
        p1[nt] = *(const uint2*)(P + (size_t)sn_[nt] * 512 + coff);
      #pragma unroll
      for (int nt = 0; nt < 4; ++nt)
        p2[nt] = *(const uint2*)(P + (size_t)dn_[nt] * 512 + 256 + coff);
      #pragma unroll
      for (int nt = 0; nt < 4; ++nt) {
        f32x4 a = acc[ctl][nt];
        float g0 = a[0] + bf2f((unsigned short)(p1[nt].x & 0xFFFFu)) + bf2f((unsigned short)(p2[nt].x & 0xFFFFu));
        float g1 = a[1] + bf2f((unsigned short)(p1[nt].x >> 16))     + bf2f((unsigned short)(p2[nt].x >> 16));
        float g2 = a[2] + bf2f((unsigned short)(p1[nt].y & 0xFFFFu)) + bf2f((unsigned short)(p2[nt].y & 0xFFFFu));
        float g3 = a[3] + bf2f((unsigned short)(p1[nt].y >> 16))     + bf2f((unsigned short)(p2[nt].y >> 16));
        if (ok_[nt]) {
          sA[ctl * 4 + 0] += g0; qA[ctl * 4 + 0] += g0 * g0;
          sA[ctl * 4 + 1] += g1; qA[ctl * 4 + 1] += g1 * g1;
          sA[ctl * 4 + 2] += g2; qA[ctl * 4 + 2] += g2 * g2;
          sA[ctl * 4 + 3] += g3; qA[ctl * 4 + 3] += g3 * g3;
          ushort4 hv = {f2bf(g0), f2bf(g1), f2bf(g2), f2bf(g3)};
          *(ushort4*)(gated + (size_t)sp_[nt] * 256 + coff) = hv;
        }
      }
    }
  }

  // flush BN1 partials: reduce over l15 (lanes differing in bits 0..3), one atomic per col
  #pragma unroll
  for (int i = 0; i < 16; ++i) {
    float s = sA[i], q = qA[i];
    #pragma unroll
    for (int m = 1; m < 16; m <<= 1) {
      s += __shfl_xor(s, m, 64);
      q += __shfl_xor(q, m, 64);
    }
    if (l15 == 0) {
      int col = w * 64 + (i >> 2) * 16 + lg * 4 + (i & 3);
      atomicAdd(&stats[col], s);
      atomicAdd(&stats[256 + col], q);
    }
  }
}

// finalize BN1: scale/shift per column (bias b cancels in BN -> ignored everywhere)
__global__ void k_bn1fin(float* __restrict__ stats, const float* __restrict__ g1,
                         const float* __restrict__ b1, float Einv) {
  int j = threadIdx.x;   // 256 threads
  float mu = stats[j] * Einv;
  float var = stats[256 + j] * Einv - mu * mu;
  float s = g1[j] * rsqrtf(var + BN_EPS);
  stats[768 + j] = s;
  stats[1024 + j] = b1[j] - mu * s;
}

// Phase 2: one wave per node: reduce its CSR run of gated rows -> summed (in d_out)
__global__ __launch_bounds__(256) void k_phase2(
    const unsigned short* __restrict__ gated,
    const int* __restrict__ offs, const int* __restrict__ deg,
    const float* __restrict__ stats, float* __restrict__ out, int N) {
  int wid = (blockIdx.x * 256 + threadIdx.x) >> 6;
  int lane = threadIdx.x & 63;
  if (wid >= N) return;
  const float* scale1 = stats + 768;
  const float* shift1 = stats + 1024;
  int c0 = lane * 2;
  float sf0 = scale1[c0], sf1 = scale1[c0 + 1];
  float hf0 = shift1[c0], hf1 = shift1[c0 + 1];
  float sc0 = scale1[128 + c0], sc1 = scale1[128 + c0 + 1];
  float hc0 = shift1[128 + c0], hc1 = shift1[128 + c0 + 1];
  int st = offs[wid], d = deg[wid];
  const unsigned short* rowp = gated + (size_t)st * 256;
  float a0 = 0.f, a1 = 0.f;
  for (int i = 0; i < d; ++i) {
    unsigned int fw = *(const unsigned int*)(rowp + c0);
    unsigned int cw = *(const unsigned int*)(rowp + 128 + c0);
    float f0 = bf2f((unsigned short)(fw & 0xFFFFu)) * sf0 + hf0;
    float f1 = bf2f((unsigned short)(fw >> 16)) * sf1 + hf1;
    float q0 = bf2f((unsigned short)(cw & 0xFFFFu)) * sc0 + hc0;
    float q1 = bf2f((unsigned short)(cw >> 16)) * sc1 + hc1;
    a0 += sigmoidf_(f0) * softplusf_(q0);
    a1 += sigmoidf_(f1) * softplusf_(q1);
    rowp += 256;
  }
  *(float2*)(out + (size_t)wid * 128 + c0) = make_float2(a0, a1);
}

// BN2 stats over summed (= d_out)
__global__ __launch_bounds__(256) void k_bn2stats(const float* __restrict__ out,
                                                  float* __restrict__ stats, int N) {
  float* sum2 = stats + 512;
  float* sq2 = stats + 640;
  __shared__ float s_[128], q_[128];
  int c = threadIdx.x & 127, h = threadIdx.x >> 7;
  float s = 0.f, q = 0.f;
  for (int r = blockIdx.x * 2 + h; r < N; r += gridDim.x * 2) {
    float v = out[(size_t)r * 128 + c];
    s += v; q += v * v;
  }
  if (h == 0) { s_[c] = s; q_[c] = q; }
  __syncthreads();
  if (h == 1) { s_[c] += s; q_[c] += q; }
  __syncthreads();
  if (h == 0) { atomicAdd(&sum2[c], s_[c]); atomicAdd(&sq2[c], q_[c]); }
}

// BN2 normalize in place
__global__ __launch_bounds__(256) void k_bn2norm(float* __restrict__ out,
                                                 const float* __restrict__ stats,
                                                 const float* __restrict__ g2,
                                                 const float* __restrict__ b2, int N) {
  const float* sum2 = stats + 512;
  const float* sq2 = stats + 640;
  float Ninv = 1.0f / (float)N;
  size_t total = (size_t)N * 32;   // float4 count
  for (size_t i = (size_t)blockIdx.x * blockDim.x + threadIdx.x; i < total;
       i += (size_t)gridDim.x * blockDim.x) {
    float4 v = *((const float4*)out + i);
    int c = (int)((i & 31) << 2);
    float r[4] = {v.x, v.y, v.z, v.w};
    #pragma unroll
    for (int j = 0; j < 4; ++j) {
      float mu = sum2[c + j] * Ninv;
      float var = sq2[c + j] * Ninv - mu * mu;
      float sc = g2[c + j] * rsqrtf(var + BN_EPS);
      r[j] = (r[j] - mu) * sc + b2[c + j];
    }
    *((float4*)out + i) = make_float4(r[0], r[1], r[2], r[3]);
  }
}

// ---------- launch ----------
extern "C" void kernel_launch(void* const* d_in, const int* in_sizes, int n_in,
                              void* d_out, int out_size, void* d_ws, size_t ws_size,
                              hipStream_t stream) {
  (void)n_in; (void)out_size;
  const float* x  = (const float*)d_in[0];
  const int*   ei = (const int*)d_in[1];
  const float* ea = (const float*)d_in[2];
  const float* W  = (const float*)d_in[3];
  const float* g1 = (const float*)d_in[5];
  const float* b1 = (const float*)d_in[6];
  const float* g2 = (const float*)d_in[7];
  const float* b2 = (const float*)d_in[8];
  int N = in_sizes[0] / 128;
  int E = in_sizes[1] / 2;
  float* out = (float*)d_out;

  // ws layout
  char* base = (char*)d_ws;
  size_t off = 0;
  auto take = [&](size_t bytes) {
    size_t o = off;
    off = (off + bytes + 255) & ~(size_t)255;
    return o;
  };
  size_t oWT12   = take((size_t)512 * 128 * sizeof(unsigned short));
  size_t oW3T    = take((size_t)256 * 64 * sizeof(unsigned short));
  size_t oP      = take((size_t)N * 512 * sizeof(unsigned short));
  size_t oGated  = take((size_t)E * 256 * sizeof(unsigned short));
  size_t oDeg    = take((size_t)N * sizeof(int));
  size_t oOffs   = take((size_t)N * sizeof(int));
  size_t oCur    = take((size_t)N * sizeof(int));
  size_t oStats  = take(2048 * sizeof(float));
  if (off > ws_size) return;

  unsigned short* WT12 = (unsigned short*)(base + oWT12);
  unsigned short* W3T  = (unsigned short*)(base + oW3T);
  unsigned short* P    = (unsigned short*)(base + oP);
  unsigned short* gated = (unsigned short*)(base + oGated);
  int* deg = (int*)(base + oDeg);
  int* offs = (int*)(base + oOffs);
  int* cursor = (int*)(base + oCur);
  float* stats = (float*)(base + oStats);

  int ntiles = (E + 63) / 64;
  k_zero<<<256, 256, 0, stream>>>(deg, stats, N);
  k_deg<<<(E / 4 + 255) / 256, 256, 0, stream>>>(ei, deg, E);
  k_scan<<<1, 1024, 0, stream>>>(deg, offs, cursor, N);
  k_wt<<<320, 256, 0, stream>>>(W, WT12, W3T);
  k_pgemm<<<dim3((N + 63) / 64, 2), 256, 0, stream>>>(x, WT12, P, N);
  k_fuse<<<2048, 256, 0, stream>>>(ei, ea, W3T, P, gated, cursor, stats, E, ntiles);
  k_bn1fin<<<1, 256, 0, stream>>>(stats, g1, b1, 1.0f / (float)E);
  k_phase2<<<(N + 3) / 4, 256, 0, stream>>>(gated, offs, deg, stats, out, N);
  k_bn2stats<<<512, 256, 0, stream>>>(out, stats, N);
  k_bn2norm<<<1024, 256, 0, stream>>>(out, stats, g2, b2, N);
}

// Round 5
// 1187.821 us; speedup vs baseline: 1.5157x; 1.5157x over previous
//
#include <hip/hip_runtime.h>
#include <hip/hip_bf16.h>
#include <math.h>

#define BN_EPS 1e-5f

typedef __bf16 bf8 __attribute__((ext_vector_type(8)));
typedef unsigned short us8 __attribute__((ext_vector_type(8)));
typedef float f32x4 __attribute__((ext_vector_type(4)));

// ---------- helpers ----------
static __device__ __forceinline__ unsigned short f2bf(float f) {
  unsigned int u = __float_as_uint(f);
  unsigned int r = (u + 0x7FFFu + ((u >> 16) & 1u)) >> 16;   // RNE
  return (unsigned short)r;
}
static __device__ __forceinline__ float bf2f(unsigned short v) {
  return __uint_as_float(((unsigned int)v) << 16);
}
static __device__ __forceinline__ float sigmoidf_(float x) {
  return 1.0f / (1.0f + __expf(-x));
}
static __device__ __forceinline__ float softplusf_(float x) {
  return fmaxf(x, 0.0f) + log1pf(__expf(-fabsf(x)));
}

// ---------- kernels ----------

// init: zero deg + stats accumulators, build WT [256 cols][320 k] bf16 (WT[c][k]=W[k][c])
__global__ void k_init(const float* __restrict__ W, unsigned short* __restrict__ WT,
                       int* __restrict__ deg, float* __restrict__ stats, int N) {
  int stride = gridDim.x * blockDim.x;
  int gid = blockIdx.x * blockDim.x + threadIdx.x;
  for (int j = gid; j < 81920; j += stride) {
    int k = j >> 8, c = j & 255;                 // coalesced read of W[k][c]
    WT[c * 320 + k] = f2bf(W[j]);
  }
  for (int j = gid; j < N; j += stride) deg[j] = 0;
  for (int j = gid; j < 768; j += stride) stats[j] = 0.f;
}

// degree count over src = edge_index[0], int4 loads
__global__ void k_deg(const int* __restrict__ ei, int* __restrict__ deg, int E) {
  int idx = blockIdx.x * 256 + threadIdx.x;
  int e = idx * 4;
  if (e + 3 < E) {
    int4 v = *(const int4*)(ei + e);
    atomicAdd(&deg[v.x], 1);
    atomicAdd(&deg[v.y], 1);
    atomicAdd(&deg[v.z], 1);
    atomicAdd(&deg[v.w], 1);
  } else if (e < E) {
    for (int k = e; k < E && k < e + 4; ++k) atomicAdd(&deg[ei[k]], 1);
  }
}

// exclusive scan of deg -> offs, copy -> cursor. Single block, 4 elems/thread.
__global__ __launch_bounds__(1024) void k_scan(const int* __restrict__ deg,
                                               int* __restrict__ offs,
                                               int* __restrict__ cursor, int N) {
  __shared__ int wsum[16];
  __shared__ int carry_s;
  int tid = threadIdx.x;
  int lane = tid & 63, wv = tid >> 6;
  if (tid == 0) carry_s = 0;
  __syncthreads();
  int N4 = (N + 3) >> 2;
  for (int b4 = 0; b4 < N4; b4 += 1024) {
    int i4 = b4 + tid;
    int4 v = make_int4(0, 0, 0, 0);
    int base = i4 * 4;
    if (i4 < N4) {
      if (base + 3 < N) v = *(const int4*)(deg + base);
      else {
        v.x = deg[base];
        if (base + 1 < N) v.y = deg[base + 1];
        if (base + 2 < N) v.z = deg[base + 2];
      }
    }
    int tsum = v.x + v.y + v.z + v.w;
    int x = tsum;
    #pragma unroll
    for (int off = 1; off < 64; off <<= 1) {
      int t = __shfl_up(x, off, 64);
      if (lane >= off) x += t;
    }
    if (lane == 63) wsum[wv] = x;
    __syncthreads();
    if (wv == 0 && lane < 16) {
      int y = wsum[lane];
      #pragma unroll
      for (int off = 1; off < 16; off <<= 1) {
        int t = __shfl_up(y, off, 64);
        if (lane >= off) y += t;
      }
      wsum[lane] = y;   // inclusive over waves
    }
    __syncthreads();
    int carry = carry_s;
    int pre = carry + ((wv == 0) ? 0 : wsum[wv - 1]) + (x - tsum);
    if (i4 < N4) {
      int o0 = pre, o1 = o0 + v.x, o2 = o1 + v.y, o3 = o2 + v.z;
      if (base + 3 < N) {
        *(int4*)(offs + base) = make_int4(o0, o1, o2, o3);
        *(int4*)(cursor + base) = make_int4(o0, o1, o2, o3);
      } else {
        offs[base] = o0; cursor[base] = o0;
        if (base + 1 < N) { offs[base + 1] = o1; cursor[base + 1] = o1; }
        if (base + 2 < N) { offs[base + 2] = o2; cursor[base + 2] = o2; }
      }
    }
    __syncthreads();
    if (tid == 1023) carry_s = carry + wsum[15];
    __syncthreads();
  }
}

// eord[cursor[src]++] = e : edge ids grouped by src node
__global__ void k_scatter(const int* __restrict__ ei, int* __restrict__ cursor,
                          int* __restrict__ eord, int E) {
  int e = blockIdx.x * 256 + threadIdx.x;
  if (e < E) {
    int p = atomicAdd(&cursor[ei[e]], 1);
    eord[p] = e;
  }
}

// Edge GEMM: per 64-edge tile: gather [xi|xj|ea]->bf16 F; gated = F @ W (K=320, MFMA,
// W staged through LDS in double-buffered 16KB k-chunks via global_load_lds);
// epilogue: BN1 stats (regs) + LDS transpose -> coalesced edge-order bf16 stores.
// Block 256 = 4 waves; wave w owns cols w*64..w*64+63, all 64 edges.
__global__ __launch_bounds__(256, 2) void k_edge(
    const int* __restrict__ ei, const float* __restrict__ x,
    const float* __restrict__ ea, const unsigned short* __restrict__ WT,
    unsigned short* __restrict__ gated, float* __restrict__ stats,
    int E, int ntiles) {
  __shared__ unsigned short F[64][328];     // [edge][k 0..319], +8 pad -> conflict-free b128
  __shared__ unsigned short WTs[2][8192];   // double-buffered k-chunk: [col 256][oct 4][8]
  __shared__ int ssrc[64], sdst[64];
  int tid = threadIdx.x;
  int w = tid >> 6, l = tid & 63, l15 = l & 15, lg = l >> 4;

  // --- per-thread invariants ---
  // stage source pointers: instr i covers LDS slots g = w*256+i*64+l; col=g>>2, oct=g&3
  // slot (col,oct) holds logical k-oct (oct ^ s(col)), s(col)=(col>>1)&3  -> conflict-free A reads
  const unsigned short* WTp[4];
  {
    int oct = l & 3;
    #pragma unroll
    for (int i = 0; i < 4; ++i) {
      int col = w * 64 + i * 16 + (l >> 2);
      int swz = oct ^ ((col >> 1) & 3);
      WTp[i] = WT + (size_t)col * 320 + swz * 8;
    }
  }
  int aoff[4], fb[4];
  #pragma unroll
  for (int ct = 0; ct < 4; ++ct) {
    int colA = w * 64 + ct * 16 + l15;
    aoff[ct] = colA * 32 + ((lg ^ ((colA >> 1) & 3)) << 3);
  }
  #pragma unroll
  for (int nt = 0; nt < 4; ++nt) fb[nt] = (nt * 16 + l15) * 328 + lg * 8;

  float sA[16] = {}, qA[16] = {};           // BN1 partials: col w*64 + (i>>2)*16 + lg*4 + (i&3)

  for (int t = blockIdx.x; t < ntiles; t += gridDim.x) {
    int e0 = t * 64;
    __syncthreads();                        // prev tile fully done -> F/ids/WTs reusable
    if (tid < 64) {
      int e = e0 + tid;
      int s = 0, d = 0;
      if (e < E) { s = ei[e]; d = ei[E + e]; }
      ssrc[tid] = s; sdst[tid] = d;
    }
    // stage chunk 0 into WTs[0] (independent of ids)
    #pragma unroll
    for (int i = 0; i < 4; ++i)
      __builtin_amdgcn_global_load_lds(
          (const __attribute__((address_space(1))) void*)(WTp[i]),
          (__attribute__((address_space(3))) void*)&WTs[0][(w * 256 + i * 64) * 8],
          16, 0, 0);
    __syncthreads();                        // ids visible

    // --- gather + fp32->bf16 into F ---
    {
      int q = tid & 31, rr = tid >> 5;
      #pragma unroll
      for (int it = 0; it < 8; ++it) {
        int r = rr + it * 8;
        float4 v = *(const float4*)(x + (size_t)ssrc[r] * 128 + q * 4);
        ushort4 h = {f2bf(v.x), f2bf(v.y), f2bf(v.z), f2bf(v.w)};
        *(ushort4*)&F[r][q * 4] = h;
      }
      #pragma unroll
      for (int it = 0; it < 8; ++it) {
        int r = rr + it * 8;
        float4 v = *(const float4*)(x + (size_t)sdst[r] * 128 + q * 4);
        ushort4 h = {f2bf(v.x), f2bf(v.y), f2bf(v.z), f2bf(v.w)};
        *(ushort4*)&F[r][128 + q * 4] = h;
      }
      int q2 = tid & 15, r4 = tid >> 4;
      #pragma unroll
      for (int it = 0; it < 4; ++it) {
        int r = r4 + it * 16;
        int e = e0 + r;
        float4 v = make_float4(0.f, 0.f, 0.f, 0.f);
        if (e < E) v = *(const float4*)(ea + (size_t)e * 64 + q2 * 4);
        ushort4 h = {f2bf(v.x), f2bf(v.y), f2bf(v.z), f2bf(v.w)};
        *(ushort4*)&F[r][256 + q2 * 4] = h;
      }
    }
    __syncthreads();                        // F + chunk 0 ready (vmcnt drained at barrier)

    // --- K loop: 10 chunks of 32 ---
    f32x4 acc[4][4] = {};                   // [ct][nt]
    #pragma unroll 2
    for (int kk = 0; kk < 10; ++kk) {
      int buf = kk & 1;
      if (kk < 9) {
        #pragma unroll
        for (int i = 0; i < 4; ++i)
          __builtin_amdgcn_global_load_lds(
              (const __attribute__((address_space(1))) void*)(WTp[i] + (kk + 1) * 32),
              (__attribute__((address_space(3))) void*)&WTs[buf ^ 1][(w * 256 + i * 64) * 8],
              16, 0, 0);
      }
      bf8 b_[4], a_[4];
      #pragma unroll
      for (int nt = 0; nt < 4; ++nt)
        b_[nt] = __builtin_bit_cast(bf8, *(const us8*)&F[0][fb[nt] + kk * 32]);
      #pragma unroll
      for (int ct = 0; ct < 4; ++ct)
        a_[ct] = __builtin_bit_cast(bf8, *(const us8*)&WTs[buf][aoff[ct]]);
      #pragma unroll
      for (int ct = 0; ct < 4; ++ct)
        #pragma unroll
        for (int nt = 0; nt < 4; ++nt)
          acc[ct][nt] = __builtin_amdgcn_mfma_f32_16x16x32_bf16(a_[ct], b_[nt], acc[ct][nt], 0, 0, 0);
      __syncthreads();                      // chunk kk consumed; chunk kk+1 staged
    }

    // --- epilogue: stats + LDS transpose (reuse F) ---
    #pragma unroll
    for (int ct = 0; ct < 4; ++ct) {
      int col0 = w * 64 + ct * 16 + lg * 4;
      #pragma unroll
      for (int nt = 0; nt < 4; ++nt) {
        int el = nt * 16 + l15;
        f32x4 a = acc[ct][nt];
        if (e0 + el < E) {
          sA[ct * 4 + 0] += a[0]; qA[ct * 4 + 0] += a[0] * a[0];
          sA[ct * 4 + 1] += a[1]; qA[ct * 4 + 1] += a[1] * a[1];
          sA[ct * 4 + 2] += a[2]; qA[ct * 4 + 2] += a[2] * a[2];
          sA[ct * 4 + 3] += a[3]; qA[ct * 4 + 3] += a[3] * a[3];
        }
        ushort4 hv = {f2bf(a[0]), f2bf(a[1]), f2bf(a[2]), f2bf(a[3])};
        *(ushort4*)&F[el][col0] = hv;
      }
    }
    __syncthreads();
    // coalesced copy F[0:rows][0:256] -> gated (edge order)
    int rows = E - e0; if (rows > 64) rows = 64;
    for (int i = tid; i < rows * 32; i += 256) {
      int r = i >> 5, c8 = (i & 31) * 8;
      *(uint4*)(gated + (size_t)(e0 + r) * 256 + c8) = *(const uint4*)&F[r][c8];
    }
  }

  // flush BN1 partials: reduce over l15, one atomic per column
  #pragma unroll
  for (int i = 0; i < 16; ++i) {
    float s = sA[i], q = qA[i];
    #pragma unroll
    for (int m = 1; m < 16; m <<= 1) {
      s += __shfl_xor(s, m, 64);
      q += __shfl_xor(q, m, 64);
    }
    if (l15 == 0) {
      int col = w * 64 + (i >> 2) * 16 + lg * 4 + (i & 3);
      atomicAdd(&stats[col], s);
      atomicAdd(&stats[256 + col], q);
    }
  }
}

// finalize BN1: scale/shift per column (bias b cancels in BN -> ignored everywhere)
__global__ void k_bn1fin(float* __restrict__ stats, const float* __restrict__ g1,
                         const float* __restrict__ b1, float Einv) {
  int j = threadIdx.x;   // 256 threads
  float mu = stats[j] * Einv;
  float var = stats[256 + j] * Einv - mu * mu;
  float s = g1[j] * rsqrtf(var + BN_EPS);
  stats[768 + j] = s;
  stats[1024 + j] = b1[j] - mu * s;
}

// Phase 2: one wave per node; gather its edges' gated rows via eord, reduce -> out
__global__ __launch_bounds__(256) void k_phase2(
    const unsigned short* __restrict__ gated,
    const int* __restrict__ offs, const int* __restrict__ deg,
    const int* __restrict__ eord, const float* __restrict__ stats,
    float* __restrict__ out, int N) {
  int wid = (blockIdx.x * 256 + threadIdx.x) >> 6;
  int lane = threadIdx.x & 63;
  if (wid >= N) return;
  const float* scale1 = stats + 768;
  const float* shift1 = stats + 1024;
  int c0 = lane * 2;
  float sf0 = scale1[c0], sf1 = scale1[c0 + 1];
  float hf0 = shift1[c0], hf1 = shift1[c0 + 1];
  float sc0 = scale1[128 + c0], sc1 = scale1[128 + c0 + 1];
  float hc0 = shift1[128 + c0], hc1 = shift1[128 + c0 + 1];
  int st = offs[wid], d = deg[wid];
  float a0 = 0.f, a1 = 0.f;
  for (int base = 0; base < d; base += 64) {
    int cnt = d - base; if (cnt > 64) cnt = 64;
    int eid = 0;
    if (lane < cnt) eid = eord[st + base + lane];
    for (int j = 0; j < cnt; ++j) {
      int e = __shfl(eid, j, 64);
      const unsigned short* rowp = gated + (size_t)e * 256;
      unsigned int fw = *(const unsigned int*)(rowp + c0);
      unsigned int cw = *(const unsigned int*)(rowp + 128 + c0);
      float f0 = bf2f((unsigned short)(fw & 0xFFFFu)) * sf0 + hf0;
      float f1 = bf2f((unsigned short)(fw >> 16)) * sf1 + hf1;
      float q0 = bf2f((unsigned short)(cw & 0xFFFFu)) * sc0 + hc0;
      float q1 = bf2f((unsigned short)(cw >> 16)) * sc1 + hc1;
      a0 += sigmoidf_(f0) * softplusf_(q0);
      a1 += sigmoidf_(f1) * softplusf_(q1);
    }
  }
  *(float2*)(out + (size_t)wid * 128 + c0) = make_float2(a0, a1);
}

// BN2 stats over summed (= d_out)
__global__ __launch_bounds__(256) void k_bn2stats(const float* __restrict__ out,
                                                  float* __restrict__ stats, int N) {
  float* sum2 = stats + 512;
  float* sq2 = stats + 640;
  __shared__ float s_[128], q_[128];
  int c = threadIdx.x & 127, h = threadIdx.x >> 7;
  float s = 0.f, q = 0.f;
  for (int r = blockIdx.x * 2 + h; r < N; r += gridDim.x * 2) {
    float v = out[(size_t)r * 128 + c];
    s += v; q += v * v;
  }
  if (h == 0) { s_[c] = s; q_[c] = q; }
  __syncthreads();
  if (h == 1) { s_[c] += s; q_[c] += q; }
  __syncthreads();
  if (h == 0) { atomicAdd(&sum2[c], s_[c]); atomicAdd(&sq2[c], q_[c]); }
}

// BN2 normalize in place
__global__ __launch_bounds__(256) void k_bn2norm(float* __restrict__ out,
                                                 const float* __restrict__ stats,
                                                 const float* __restrict__ g2,
                                                 const float* __restrict__ b2, int N) {
  const float* sum2 = stats + 512;
  const float* sq2 = stats + 640;
  float Ninv = 1.0f / (float)N;
  size_t total = (size_t)N * 32;   // float4 count
  for (size_t i = (size_t)blockIdx.x * blockDim.x + threadIdx.x; i < total;
       i += (size_t)gridDim.x * blockDim.x) {
    float4 v = *((const float4*)out + i);
    int c = (int)((i & 31) << 2);
    float r[4] = {v.x, v.y, v.z, v.w};
    #pragma unroll
    for (int j = 0; j < 4; ++j) {
      float mu = sum2[c + j] * Ninv;
      float var = sq2[c + j] * Ninv - mu * mu;
      float sc = g2[c + j] * rsqrtf(var + BN_EPS);
      r[j] = (r[j] - mu) * sc + b2[c + j];
    }
    *((float4*)out + i) = make_float4(r[0], r[1], r[2], r[3]);
  }
}

// ---------- launch ----------
extern "C" void kernel_launch(void* const* d_in, const int* in_sizes, int n_in,
                              void* d_out, int out_size, void* d_ws, size_t ws_size,
                              hipStream_t stream) {
  (void)n_in; (void)out_size;
  const float* x  = (const float*)d_in[0];
  const int*   ei = (const int*)d_in[1];
  const float* ea = (const float*)d_in[2];
  const float* W  = (const float*)d_in[3];
  const float* g1 = (const float*)d_in[5];
  const float* b1 = (const float*)d_in[6];
  const float* g2 = (const float*)d_in[7];
  const float* b2 = (const float*)d_in[8];
  int N = in_sizes[0] / 128;
  int E = in_sizes[1] / 2;
  float* out = (float*)d_out;

  // ws layout
  char* base = (char*)d_ws;
  size_t off = 0;
  auto take = [&](size_t bytes) {
    size_t o = off;
    off = (off + bytes + 255) & ~(size_t)255;
    return o;
  };
  size_t oWT     = take((size_t)256 * 320 * sizeof(unsigned short));
  size_t oGated  = take((size_t)E * 256 * sizeof(unsigned short));
  size_t oDeg    = take((size_t)N * sizeof(int));
  size_t oOffs   = take((size_t)N * sizeof(int));
  size_t oCur    = take((size_t)N * sizeof(int));
  size_t oEord   = take((size_t)E * sizeof(int));
  size_t oStats  = take(2048 * sizeof(float));
  if (off > ws_size) return;

  unsigned short* WT = (unsigned short*)(base + oWT);
  unsigned short* gated = (unsigned short*)(base + oGated);
  int* deg = (int*)(base + oDeg);
  int* offs = (int*)(base + oOffs);
  int* cursor = (int*)(base + oCur);
  int* eord = (int*)(base + oEord);
  float* stats = (float*)(base + oStats);

  int ntiles = (E + 63) / 64;
  k_init<<<512, 256, 0, stream>>>(W, WT, deg, stats, N);
  k_deg<<<(E / 4 + 255) / 256, 256, 0, stream>>>(ei, deg, E);
  k_scan<<<1, 1024, 0, stream>>>(deg, offs, cursor, N);
  k_scatter<<<(E + 255) / 256, 256, 0, stream>>>(ei, cursor, eord, E);
  k_edge<<<512, 256, 0, stream>>>(ei, x, ea, WT, gated, stats, E, ntiles);
  k_bn1fin<<<1, 256, 0, stream>>>(stats, g1, b1, 1.0f / (float)E);
  k_phase2<<<(N + 3) / 4, 256, 0, stream>>>(gated, offs, deg, eord, stats, out, N);
  k_bn2stats<<<512, 256, 0, stream>>>(out, stats, N);
  k_bn2norm<<<1024, 256, 0, stream>>>(out, stats, g2, b2, N);
}